// Round 1
// baseline (681.805 us; speedup 1.0000x reference)
//
#include <hip/hip_runtime.h>
#include <hip/hip_bf16.h>

#define T_TOK 16384
#define D_DIM 1024
#define E_EXP 8

#define BM 128
#define BN 128
#define BK 32
#define LDSS 56   // padded bf16 stride: 112B = 7*16B (aligned, conflict-free)

typedef __attribute__((ext_vector_type(4))) float f32x4;
typedef __attribute__((ext_vector_type(8))) short bf16x8;
typedef __attribute__((ext_vector_type(4))) unsigned short u16x4;

static __device__ __forceinline__ unsigned short f2bf(float f) {
    unsigned int u = __float_as_uint(f);
    unsigned int r = 0x7FFFu + ((u >> 16) & 1u);
    return (unsigned short)((u + r) >> 16);
}

// ---------------- expert_w fp32 -> bf16 ----------------
__global__ __launch_bounds__(256) void convert_w_kernel(
    const float* __restrict__ w, unsigned short* __restrict__ o) {
    const int n4 = (E_EXP * D_DIM * D_DIM) / 4;
    for (int i = blockIdx.x * 256 + threadIdx.x; i < n4; i += gridDim.x * 256) {
        f32x4 v = ((const f32x4*)w)[i];
        u16x4 p;
        p[0] = f2bf(v[0]); p[1] = f2bf(v[1]); p[2] = f2bf(v[2]); p[3] = f2bf(v[3]);
        ((u16x4*)o)[i] = p;
    }
}

// ---------------- router: logits, softmax, top-2, gather lists ----------------
__global__ __launch_bounds__(256) void router_kernel(
    const float* __restrict__ x, const float* __restrict__ gate_w,
    const float* __restrict__ gate_b, float* __restrict__ out_logits,
    float* __restrict__ out_sel, int* __restrict__ counts,
    int* __restrict__ pair_token, float* __restrict__ pair_weight) {
    __shared__ float gw[E_EXP][D_DIM];   // 32 KB
    for (int i = threadIdx.x; i < E_EXP * D_DIM; i += 256) gw[0][i] = gate_w[i];
    __syncthreads();
    const int lane = threadIdx.x & 63;
    const int t = blockIdx.x * 4 + (threadIdx.x >> 6);   // one wave per token

    float acc[E_EXP] = {};
    const f32x4* xr = (const f32x4*)(x + (size_t)t * D_DIM);
    for (int i = lane; i < D_DIM / 4; i += 64) {
        f32x4 xv = xr[i];
        #pragma unroll
        for (int e = 0; e < E_EXP; ++e) {
            f32x4 gv = ((const f32x4*)(&gw[e][0]))[i];
            acc[e] += xv[0] * gv[0] + xv[1] * gv[1] + xv[2] * gv[2] + xv[3] * gv[3];
        }
    }
    #pragma unroll
    for (int e = 0; e < E_EXP; ++e) {
        float v = acc[e];
        #pragma unroll
        for (int off = 32; off > 0; off >>= 1) v += __shfl_xor(v, off, 64);
        acc[e] = v;
    }
    if (lane == 0) {
        float l[E_EXP], p[E_EXP];
        float m = -1e30f;
        #pragma unroll
        for (int e = 0; e < E_EXP; ++e) { l[e] = acc[e] + gate_b[e]; m = fmaxf(m, l[e]); }
        float s = 0.f;
        #pragma unroll
        for (int e = 0; e < E_EXP; ++e) { p[e] = expf(l[e] - m); s += p[e]; }
        #pragma unroll
        for (int e = 0; e < E_EXP; ++e) p[e] /= s;
        // top-2 on probs, strict > => lowest index wins ties (matches jax.lax.top_k)
        int e0 = 0; float p0 = p[0];
        #pragma unroll
        for (int e = 1; e < E_EXP; ++e) if (p[e] > p0) { p0 = p[e]; e0 = e; }
        int e1 = -1; float p1 = -1e30f;
        #pragma unroll
        for (int e = 0; e < E_EXP; ++e) if (e != e0 && p[e] > p1) { p1 = p[e]; e1 = e; }
        float denom = p0 + p1;
        float w0 = p0 / denom, w1 = p1 / denom;
        #pragma unroll
        for (int e = 0; e < E_EXP; ++e) out_logits[t * E_EXP + e] = l[e];
        out_sel[t * 2 + 0] = (float)e0;
        out_sel[t * 2 + 1] = (float)e1;
        int pos0 = atomicAdd(&counts[e0], 1);
        pair_token[e0 * T_TOK + pos0] = t;
        pair_weight[e0 * T_TOK + pos0] = w0;
        int pos1 = atomicAdd(&counts[e1], 1);
        pair_token[e1 * T_TOK + pos1] = t;
        pair_weight[e1 * T_TOK + pos1] = w1;
    }
}

// ---------------- grouped gather-GEMM: out[t] += w * (W_e x_t + b_e) ----------------
__global__ __launch_bounds__(256) void moe_gemm_kernel(
    const float* __restrict__ x, const unsigned short* __restrict__ wbf,
    const float* __restrict__ expert_b, const int* __restrict__ counts,
    const int* __restrict__ pair_token, const float* __restrict__ pair_weight,
    float* __restrict__ out) {
    const int e = blockIdx.z;
    const int cnt = counts[e];
    const int m_base = blockIdx.y * BM;
    if (m_base >= cnt) return;
    const int n_base = blockIdx.x * BN;

    __shared__ unsigned short As[BM][LDSS];
    __shared__ unsigned short Bs[BN][LDSS];
    __shared__ int tok_s[BM];
    __shared__ float w_s[BM];

    const int tid = threadIdx.x;
    if (tid < BM) {
        int m = m_base + tid;
        tok_s[tid] = (m < cnt) ? pair_token[e * T_TOK + m] : -1;
        w_s[tid]   = (m < cnt) ? pair_weight[e * T_TOK + m] : 0.f;
    }
    const int lane = tid & 63;
    const int wid = tid >> 6;
    const int wr = wid >> 1, wc = wid & 1;   // 2x2 waves, 64x64 each
    const int lr = lane & 15, lk = lane >> 4;

    f32x4 acc[4][4] = {};
    const unsigned short* wb = wbf + ((size_t)e << 20);
    __syncthreads();   // tok_s/w_s ready; also fences LDS for first staging

    for (int k0 = 0; k0 < D_DIM; k0 += BK) {
        // stage A: gathered x rows, fp32 -> bf16 (128 rows x 32 k)
        #pragma unroll
        for (int r = 0; r < 4; ++r) {
            int q = r * 256 + tid;          // [0,1024)
            int row = q >> 3;
            int col = (q & 7) << 2;
            int tk = tok_s[row];
            f32x4 v = {};
            if (tk >= 0) v = *(const f32x4*)(x + (size_t)tk * D_DIM + k0 + col);
            u16x4 pk;
            pk[0] = f2bf(v[0]); pk[1] = f2bf(v[1]); pk[2] = f2bf(v[2]); pk[3] = f2bf(v[3]);
            *(u16x4*)(&As[row][col]) = pk;
        }
        // stage B: W_e rows n_base..n_base+127 (bf16), k-chunk
        #pragma unroll
        for (int r = 0; r < 2; ++r) {
            int o = r * 256 + tid;          // [0,512)
            int row = o >> 2;
            int col = (o & 3) << 3;
            bf16x8 v = *(const bf16x8*)(wb + (size_t)(n_base + row) * D_DIM + k0 + col);
            *(bf16x8*)(&Bs[row][col]) = v;
        }
        __syncthreads();
        bf16x8 a[4], b[4];
        #pragma unroll
        for (int m = 0; m < 4; ++m)
            a[m] = *(const bf16x8*)(&As[wr * 64 + m * 16 + lr][lk * 8]);
        #pragma unroll
        for (int n = 0; n < 4; ++n)
            b[n] = *(const bf16x8*)(&Bs[wc * 64 + n * 16 + lr][lk * 8]);
        #pragma unroll
        for (int m = 0; m < 4; ++m)
            #pragma unroll
            for (int n = 0; n < 4; ++n)
                acc[m][n] = __builtin_amdgcn_mfma_f32_16x16x32_bf16(a[m], b[n], acc[m][n], 0, 0, 0);
        __syncthreads();
    }

    // epilogue: out[t, gn] += w * (acc + bias)
    float bias[4];
    #pragma unroll
    for (int n = 0; n < 4; ++n) {
        int gn = n_base + wc * 64 + n * 16 + lr;
        bias[n] = expert_b[e * D_DIM + gn];
    }
    #pragma unroll
    for (int m = 0; m < 4; ++m) {
        #pragma unroll
        for (int j = 0; j < 4; ++j) {
            int mi = wr * 64 + m * 16 + lk * 4 + j;
            int tk = tok_s[mi];
            if (tk < 0) continue;
            float w = w_s[mi];
            size_t obase = (size_t)tk * D_DIM;
            #pragma unroll
            for (int n = 0; n < 4; ++n) {
                int gn = n_base + wc * 64 + n * 16 + lr;
                atomicAdd(out + obase + gn, (acc[m][n][j] + bias[n]) * w);
            }
        }
    }
}

extern "C" void kernel_launch(void* const* d_in, const int* in_sizes, int n_in,
                              void* d_out, int out_size, void* d_ws, size_t ws_size,
                              hipStream_t stream) {
    const float* x        = (const float*)d_in[0];
    const float* gate_w   = (const float*)d_in[1];
    const float* gate_b   = (const float*)d_in[2];
    const float* expert_w = (const float*)d_in[3];
    const float* expert_b = (const float*)d_in[4];

    float* out        = (float*)d_out;                     // [T, D]
    float* out_logits = out + (size_t)T_TOK * D_DIM;       // [T, E]
    float* out_sel    = out_logits + (size_t)T_TOK * E_EXP; // [T, 2] as float

    char* ws = (char*)d_ws;
    unsigned short* wbf = (unsigned short*)ws;                        // 16,777,216 B
    int*   counts      = (int*)(ws + 16777216);                       // 32 B (+pad)
    int*   pair_token  = (int*)(ws + 16777216 + 256);                 // E*T*4
    float* pair_weight = (float*)(ws + 16777216 + 256 + 524288);      // E*T*4

    hipMemsetAsync(counts, 0, E_EXP * sizeof(int), stream);
    hipMemsetAsync(out, 0, (size_t)T_TOK * D_DIM * sizeof(float), stream);

    convert_w_kernel<<<2048, 256, 0, stream>>>(expert_w, wbf);
    router_kernel<<<T_TOK / 4, 256, 0, stream>>>(x, gate_w, gate_b, out_logits,
                                                 out_sel, counts, pair_token, pair_weight);
    dim3 grid(D_DIM / BN, T_TOK / BM, E_EXP);
    moe_gemm_kernel<<<grid, 256, 0, stream>>>(x, wbf, expert_b, counts,
                                              pair_token, pair_weight, out);
}

// Round 2
// 323.030 us; speedup vs baseline: 2.1107x; 2.1107x over previous
//
#include <hip/hip_runtime.h>
#include <hip/hip_bf16.h>

#define T_TOK 16384
#define D_DIM 1024
#define E_EXP 8

#define BM 128
#define BN 128
#define BK 32
#define LDSS 56   // padded bf16 stride: 112B = 7*16B (aligned, conflict-free)

#define CNT_STRIDE 64   // pad expert counters to 256B apart

typedef __attribute__((ext_vector_type(4))) float f32x4;
typedef __attribute__((ext_vector_type(8))) short bf16x8;
typedef __attribute__((ext_vector_type(4))) unsigned short u16x4;

static __device__ __forceinline__ unsigned short f2bf(float f) {
    unsigned int u = __float_as_uint(f);
    unsigned int r = 0x7FFFu + ((u >> 16) & 1u);
    return (unsigned short)((u + r) >> 16);
}

// ---------------- expert_w fp32 -> bf16 ----------------
__global__ __launch_bounds__(256) void convert_w_kernel(
    const float* __restrict__ w, unsigned short* __restrict__ o) {
    const int n4 = (E_EXP * D_DIM * D_DIM) / 4;
    for (int i = blockIdx.x * 256 + threadIdx.x; i < n4; i += gridDim.x * 256) {
        f32x4 v = ((const f32x4*)w)[i];
        u16x4 p;
        p[0] = f2bf(v[0]); p[1] = f2bf(v[1]); p[2] = f2bf(v[2]); p[3] = f2bf(v[3]);
        ((u16x4*)o)[i] = p;
    }
}

// ---------------- router: 64 tokens/block, LDS-aggregated scatter ----------------
#define TPB_TOK 64
__global__ __launch_bounds__(256) void router_kernel(
    const float* __restrict__ x, const float* __restrict__ gate_w,
    const float* __restrict__ gate_b, float* __restrict__ out_logits,
    float* __restrict__ out_sel, int* __restrict__ counts,
    int* __restrict__ pair_token, float* __restrict__ pair_weight) {
    __shared__ float gw[E_EXP][D_DIM];          // 32 KB
    __shared__ float gb_s[E_EXP];
    __shared__ float logits_s[TPB_TOK][E_EXP];  // 2 KB
    __shared__ int   cnt_local[E_EXP];
    __shared__ int   gbase[E_EXP];
    __shared__ int   ent_e[TPB_TOK][2];
    __shared__ int   ent_pos[TPB_TOK][2];
    __shared__ float ent_w[TPB_TOK][2];

    const int tid = threadIdx.x;
    for (int i = tid; i < E_EXP * D_DIM; i += 256) gw[0][i] = gate_w[i];
    if (tid < E_EXP) { gb_s[tid] = gate_b[tid]; cnt_local[tid] = 0; }
    __syncthreads();

    const int lane = tid & 63, wv = tid >> 6;
    const int tl = lane >> 2, g = lane & 3;     // 4 lanes per token
    const int jt = wv * 16 + tl;                // token within block [0,64)
    const int t = blockIdx.x * TPB_TOK + jt;

    float acc[E_EXP] = {};
    const f32x4* xr = (const f32x4*)(x + (size_t)t * D_DIM);
    for (int i = g; i < D_DIM / 4; i += 4) {
        f32x4 xv = xr[i];
        #pragma unroll
        for (int e = 0; e < E_EXP; ++e) {
            f32x4 gv = ((const f32x4*)(&gw[e][0]))[i];
            acc[e] += xv[0] * gv[0] + xv[1] * gv[1] + xv[2] * gv[2] + xv[3] * gv[3];
        }
    }
    #pragma unroll
    for (int e = 0; e < E_EXP; ++e) {
        float v = acc[e];
        v += __shfl_xor(v, 1, 64);
        v += __shfl_xor(v, 2, 64);
        acc[e] = v;
    }
    if (g == 0) {
        float l[E_EXP], p[E_EXP];
        float m = -1e30f;
        #pragma unroll
        for (int e = 0; e < E_EXP; ++e) { l[e] = acc[e] + gb_s[e]; m = fmaxf(m, l[e]); }
        float s = 0.f;
        #pragma unroll
        for (int e = 0; e < E_EXP; ++e) { p[e] = expf(l[e] - m); s += p[e]; }
        #pragma unroll
        for (int e = 0; e < E_EXP; ++e) p[e] /= s;
        // top-2 on probs, strict > => lowest index wins ties (matches jax.lax.top_k)
        int e0 = 0; float p0 = p[0];
        #pragma unroll
        for (int e = 1; e < E_EXP; ++e) if (p[e] > p0) { p0 = p[e]; e0 = e; }
        int e1 = -1; float p1 = -1e30f;
        #pragma unroll
        for (int e = 0; e < E_EXP; ++e) if (e != e0 && p[e] > p1) { p1 = p[e]; e1 = e; }
        float denom = p0 + p1;
        float w0 = p0 / denom, w1 = p1 / denom;
        #pragma unroll
        for (int e = 0; e < E_EXP; ++e) logits_s[jt][e] = l[e];
        out_sel[t * 2 + 0] = (float)e0;
        out_sel[t * 2 + 1] = (float)e1;
        int p0i = atomicAdd(&cnt_local[e0], 1);   // LDS atomic: cheap
        int p1i = atomicAdd(&cnt_local[e1], 1);
        ent_e[jt][0] = e0; ent_pos[jt][0] = p0i; ent_w[jt][0] = w0;
        ent_e[jt][1] = e1; ent_pos[jt][1] = p1i; ent_w[jt][1] = w1;
    }
    __syncthreads();
    if (tid < E_EXP) gbase[tid] = atomicAdd(&counts[tid * CNT_STRIDE], cnt_local[tid]);
    if (tid < TPB_TOK * E_EXP / 4) {
        f32x4 v = ((const f32x4*)&logits_s[0][0])[tid];
        ((f32x4*)(out_logits + (size_t)blockIdx.x * TPB_TOK * E_EXP))[tid] = v;
    }
    __syncthreads();
    if (g == 0) {
        #pragma unroll
        for (int k = 0; k < 2; ++k) {
            int e = ent_e[jt][k];
            int pos = gbase[e] + ent_pos[jt][k];
            pair_token[e * T_TOK + pos] = t;
            pair_weight[e * T_TOK + pos] = ent_w[jt][k];
        }
    }
}

// ---------------- grouped gather-GEMM: out[t] += w * (W_e x_t + b_e) ----------------
__global__ __launch_bounds__(256) void moe_gemm_kernel(
    const float* __restrict__ x, const unsigned short* __restrict__ wbf,
    const float* __restrict__ expert_b, const int* __restrict__ counts,
    const int* __restrict__ pair_token, const float* __restrict__ pair_weight,
    float* __restrict__ out) {
    const int e = blockIdx.z;
    const int cnt = counts[e * CNT_STRIDE];
    const int m_base = blockIdx.y * BM;
    if (m_base >= cnt) return;
    const int n_base = blockIdx.x * BN;

    __shared__ unsigned short As[BM][LDSS];
    __shared__ unsigned short Bs[BN][LDSS];
    __shared__ int tok_s[BM];
    __shared__ float w_s[BM];

    const int tid = threadIdx.x;
    if (tid < BM) {
        int m = m_base + tid;
        tok_s[tid] = (m < cnt) ? pair_token[e * T_TOK + m] : -1;
        w_s[tid]   = (m < cnt) ? pair_weight[e * T_TOK + m] : 0.f;
    }
    const int lane = tid & 63;
    const int wid = tid >> 6;
    const int wr = wid >> 1, wc = wid & 1;   // 2x2 waves, 64x64 each
    const int lr = lane & 15, lk = lane >> 4;

    f32x4 acc[4][4] = {};
    const unsigned short* wb = wbf + ((size_t)e << 20);
    __syncthreads();   // tok_s/w_s ready; also fences LDS for first staging

    for (int k0 = 0; k0 < D_DIM; k0 += BK) {
        // stage A: gathered x rows, fp32 -> bf16 (128 rows x 32 k)
        #pragma unroll
        for (int r = 0; r < 4; ++r) {
            int q = r * 256 + tid;          // [0,1024)
            int row = q >> 3;
            int col = (q & 7) << 2;
            int tk = tok_s[row];
            f32x4 v = {};
            if (tk >= 0) v = *(const f32x4*)(x + (size_t)tk * D_DIM + k0 + col);
            u16x4 pk;
            pk[0] = f2bf(v[0]); pk[1] = f2bf(v[1]); pk[2] = f2bf(v[2]); pk[3] = f2bf(v[3]);
            *(u16x4*)(&As[row][col]) = pk;
        }
        // stage B: W_e rows n_base..n_base+127 (bf16), k-chunk
        #pragma unroll
        for (int r = 0; r < 2; ++r) {
            int o = r * 256 + tid;          // [0,512)
            int row = o >> 2;
            int col = (o & 3) << 3;
            bf16x8 v = *(const bf16x8*)(wb + (size_t)(n_base + row) * D_DIM + k0 + col);
            *(bf16x8*)(&Bs[row][col]) = v;
        }
        __syncthreads();
        bf16x8 a[4], b[4];
        #pragma unroll
        for (int m = 0; m < 4; ++m)
            a[m] = *(const bf16x8*)(&As[wr * 64 + m * 16 + lr][lk * 8]);
        #pragma unroll
        for (int n = 0; n < 4; ++n)
            b[n] = *(const bf16x8*)(&Bs[wc * 64 + n * 16 + lr][lk * 8]);
        #pragma unroll
        for (int m = 0; m < 4; ++m)
            #pragma unroll
            for (int n = 0; n < 4; ++n)
                acc[m][n] = __builtin_amdgcn_mfma_f32_16x16x32_bf16(a[m], b[n], acc[m][n], 0, 0, 0);
        __syncthreads();
    }

    // epilogue: out[t, gn] += w * (acc + bias)
    float bias[4];
    #pragma unroll
    for (int n = 0; n < 4; ++n) {
        int gn = n_base + wc * 64 + n * 16 + lr;
        bias[n] = expert_b[e * D_DIM + gn];
    }
    #pragma unroll
    for (int m = 0; m < 4; ++m) {
        #pragma unroll
        for (int j = 0; j < 4; ++j) {
            int mi = wr * 64 + m * 16 + lk * 4 + j;
            int tk = tok_s[mi];
            if (tk < 0) continue;
            float w = w_s[mi];
            size_t obase = (size_t)tk * D_DIM;
            #pragma unroll
            for (int n = 0; n < 4; ++n) {
                int gn = n_base + wc * 64 + n * 16 + lr;
                atomicAdd(out + obase + gn, (acc[m][n][j] + bias[n]) * w);
            }
        }
    }
}

extern "C" void kernel_launch(void* const* d_in, const int* in_sizes, int n_in,
                              void* d_out, int out_size, void* d_ws, size_t ws_size,
                              hipStream_t stream) {
    const float* x        = (const float*)d_in[0];
    const float* gate_w   = (const float*)d_in[1];
    const float* gate_b   = (const float*)d_in[2];
    const float* expert_w = (const float*)d_in[3];
    const float* expert_b = (const float*)d_in[4];

    float* out        = (float*)d_out;                      // [T, D]
    float* out_logits = out + (size_t)T_TOK * D_DIM;        // [T, E]
    float* out_sel    = out_logits + (size_t)T_TOK * E_EXP; // [T, 2] as float

    char* ws = (char*)d_ws;
    unsigned short* wbf = (unsigned short*)ws;                        // 16,777,216 B
    int*   counts      = (int*)(ws + 16777216);                       // 8*64 ints = 2 KB
    int*   pair_token  = (int*)(ws + 16777216 + 4096);                // E*T*4
    float* pair_weight = (float*)(ws + 16777216 + 4096 + 524288);     // E*T*4

    hipMemsetAsync(counts, 0, E_EXP * CNT_STRIDE * sizeof(int), stream);
    hipMemsetAsync(out, 0, (size_t)T_TOK * D_DIM * sizeof(float), stream);

    convert_w_kernel<<<2048, 256, 0, stream>>>(expert_w, wbf);
    router_kernel<<<T_TOK / TPB_TOK, 256, 0, stream>>>(x, gate_w, gate_b, out_logits,
                                                       out_sel, counts, pair_token, pair_weight);
    dim3 grid(D_DIM / BN, T_TOK / BM, E_EXP);
    moe_gemm_kernel<<<grid, 256, 0, stream>>>(x, wbf, expert_b, counts,
                                              pair_token, pair_weight, out);
}

// Round 3
// 229.321 us; speedup vs baseline: 2.9732x; 1.4086x over previous
//
#include <hip/hip_runtime.h>
#include <hip/hip_bf16.h>

#define T_TOK 16384
#define D_DIM 1024
#define E_EXP 8

#define BM 128
#define BN 128
#define BK 64            // 128 B/row in bf16

#define CNT_STRIDE 64    // pad expert counters to 256B apart

typedef __attribute__((ext_vector_type(4))) float f32x4;
typedef __attribute__((ext_vector_type(8))) short bf16x8;
typedef __attribute__((ext_vector_type(4))) unsigned short u16x4;

static __device__ __forceinline__ unsigned short f2bf(float f) {
    unsigned int u = __float_as_uint(f);
    unsigned int r = 0x7FFFu + ((u >> 16) & 1u);
    return (unsigned short)((u + r) >> 16);
}

// direct-to-LDS 16B async copy: global src per-lane, LDS dest = uniform base + lane*16
#define GLOAD_LDS16(gp, lp) \
    __builtin_amdgcn_global_load_lds( \
        (const __attribute__((address_space(1))) void*)(gp), \
        (__attribute__((address_space(3))) void*)(lp), 16, 0, 0)

// ---------------- expert_w fp32 -> bf16 ----------------
__global__ __launch_bounds__(256) void convert_w_kernel(
    const float* __restrict__ w, unsigned short* __restrict__ o) {
    const int n4 = (E_EXP * D_DIM * D_DIM) / 4;
    for (int i = blockIdx.x * 256 + threadIdx.x; i < n4; i += gridDim.x * 256) {
        f32x4 v = ((const f32x4*)w)[i];
        u16x4 p;
        p[0] = f2bf(v[0]); p[1] = f2bf(v[1]); p[2] = f2bf(v[2]); p[3] = f2bf(v[3]);
        ((u16x4*)o)[i] = p;
    }
}

// ---------------- router: 64 tokens/block + fused x->bf16 ----------------
#define TPB_TOK 64
__global__ __launch_bounds__(256) void router_kernel(
    const float* __restrict__ x, const float* __restrict__ gate_w,
    const float* __restrict__ gate_b, float* __restrict__ out_logits,
    float* __restrict__ out_sel, int* __restrict__ counts,
    int* __restrict__ pair_token, float* __restrict__ pair_weight,
    unsigned short* __restrict__ xbf) {
    __shared__ float gw[E_EXP][D_DIM];          // 32 KB
    __shared__ float gb_s[E_EXP];
    __shared__ float logits_s[TPB_TOK][E_EXP];  // 2 KB
    __shared__ int   cnt_local[E_EXP];
    __shared__ int   gbase[E_EXP];
    __shared__ int   ent_e[TPB_TOK][2];
    __shared__ int   ent_pos[TPB_TOK][2];
    __shared__ float ent_w[TPB_TOK][2];

    const int tid = threadIdx.x;
    for (int i = tid; i < E_EXP * D_DIM; i += 256) gw[0][i] = gate_w[i];
    if (tid < E_EXP) { gb_s[tid] = gate_b[tid]; cnt_local[tid] = 0; }
    __syncthreads();

    const int lane = tid & 63, wv = tid >> 6;
    const int tl = lane >> 2, g = lane & 3;     // 4 lanes per token
    const int jt = wv * 16 + tl;                // token within block [0,64)
    const int t = blockIdx.x * TPB_TOK + jt;

    float acc[E_EXP] = {};
    const f32x4* xr = (const f32x4*)(x + (size_t)t * D_DIM);
    u16x4* xw = (u16x4*)(xbf + (size_t)t * D_DIM);
    for (int i = g; i < D_DIM / 4; i += 4) {
        f32x4 xv = xr[i];
        u16x4 pk;
        pk[0] = f2bf(xv[0]); pk[1] = f2bf(xv[1]); pk[2] = f2bf(xv[2]); pk[3] = f2bf(xv[3]);
        xw[i] = pk;                              // fused fp32->bf16 copy of x
        #pragma unroll
        for (int e = 0; e < E_EXP; ++e) {
            f32x4 gv = ((const f32x4*)(&gw[e][0]))[i];
            acc[e] += xv[0] * gv[0] + xv[1] * gv[1] + xv[2] * gv[2] + xv[3] * gv[3];
        }
    }
    #pragma unroll
    for (int e = 0; e < E_EXP; ++e) {
        float v = acc[e];
        v += __shfl_xor(v, 1, 64);
        v += __shfl_xor(v, 2, 64);
        acc[e] = v;
    }
    if (g == 0) {
        float l[E_EXP], p[E_EXP];
        float m = -1e30f;
        #pragma unroll
        for (int e = 0; e < E_EXP; ++e) { l[e] = acc[e] + gb_s[e]; m = fmaxf(m, l[e]); }
        float s = 0.f;
        #pragma unroll
        for (int e = 0; e < E_EXP; ++e) { p[e] = expf(l[e] - m); s += p[e]; }
        #pragma unroll
        for (int e = 0; e < E_EXP; ++e) p[e] /= s;
        // top-2 on probs, strict > => lowest index wins ties (matches jax.lax.top_k)
        int e0 = 0; float p0 = p[0];
        #pragma unroll
        for (int e = 1; e < E_EXP; ++e) if (p[e] > p0) { p0 = p[e]; e0 = e; }
        int e1 = -1; float p1 = -1e30f;
        #pragma unroll
        for (int e = 0; e < E_EXP; ++e) if (e != e0 && p[e] > p1) { p1 = p[e]; e1 = e; }
        float denom = p0 + p1;
        float w0 = p0 / denom, w1 = p1 / denom;
        #pragma unroll
        for (int e = 0; e < E_EXP; ++e) logits_s[jt][e] = l[e];
        out_sel[t * 2 + 0] = (float)e0;
        out_sel[t * 2 + 1] = (float)e1;
        int p0i = atomicAdd(&cnt_local[e0], 1);   // LDS atomic: cheap
        int p1i = atomicAdd(&cnt_local[e1], 1);
        ent_e[jt][0] = e0; ent_pos[jt][0] = p0i; ent_w[jt][0] = w0;
        ent_e[jt][1] = e1; ent_pos[jt][1] = p1i; ent_w[jt][1] = w1;
    }
    __syncthreads();
    if (tid < E_EXP) gbase[tid] = atomicAdd(&counts[tid * CNT_STRIDE], cnt_local[tid]);
    if (tid < TPB_TOK * E_EXP / 4) {
        f32x4 v = ((const f32x4*)&logits_s[0][0])[tid];
        ((f32x4*)(out_logits + (size_t)blockIdx.x * TPB_TOK * E_EXP))[tid] = v;
    }
    __syncthreads();
    if (g == 0) {
        #pragma unroll
        for (int k = 0; k < 2; ++k) {
            int e = ent_e[jt][k];
            int pos = gbase[e] + ent_pos[jt][k];
            pair_token[e * T_TOK + pos] = t;
            pair_weight[e * T_TOK + pos] = ent_w[jt][k];
        }
    }
}

// ---------------- grouped gather-GEMM (m97 structure): out[t] += w*(W_e x_t + b_e) ----
// A,B staged via global_load_lds width=16, linear LDS, both-sides XOR swizzle:
//   LDS(row, cb) holds global (row, cb ^ ((row&7)<<4))
__global__ __launch_bounds__(256) void moe_gemm_kernel(
    const unsigned short* __restrict__ xbf, const unsigned short* __restrict__ wbf,
    const float* __restrict__ expert_b, const int* __restrict__ counts,
    const int* __restrict__ pair_token, const float* __restrict__ pair_weight,
    float* __restrict__ out) {
    const int e = blockIdx.z;
    const int cnt = counts[e * CNT_STRIDE];
    const int m_base = blockIdx.y * BM;
    if (m_base >= cnt) return;
    const int n_base = blockIdx.x * BN;

    __shared__ unsigned short As[BM * BK];   // 16 KB, linear (swizzled content)
    __shared__ unsigned short Bs[BN * BK];   // 16 KB
    __shared__ int tok_s[BM];
    __shared__ float w_s[BM];

    const int tid = threadIdx.x;
    if (tid < BM) {
        int m = m_base + tid;
        int mc = (m < cnt) ? m : (cnt - 1);  // clamp: OOB rows compute garbage, skipped in epilogue
        tok_s[tid] = pair_token[e * T_TOK + mc];
        w_s[tid]   = pair_weight[e * T_TOK + mc];
    }
    __syncthreads();

    const int lane = tid & 63;
    const int w = tid >> 6;
    const int lr = lane & 15, lk = lane >> 4;
    const int wr = w >> 1, wc = w & 1;       // 2x2 waves, 64x64 each

    // staging geometry: wave w, issue i covers rows [i*32+w*8, +8), 128 B each
    const int srow = lane >> 3;                       // row within 8-row group
    const int scol = 8 * ((lane & 7) ^ srow);         // swizzled source column (elems)
    const unsigned short* wb = wbf + ((size_t)e << 20);
    const unsigned short* agp[4];
    const unsigned short* bgp[4];
    unsigned short* alp[4];
    unsigned short* blp[4];
    #pragma unroll
    for (int i = 0; i < 4; ++i) {
        int R = i * 32 + w * 8 + srow;
        agp[i] = xbf + (size_t)tok_s[R] * D_DIM + scol;
        bgp[i] = wb + (size_t)(n_base + R) * D_DIM + scol;
        alp[i] = &As[(i * 32 + w * 8) * BK];          // wave-uniform
        blp[i] = &Bs[(i * 32 + w * 8) * BK];
    }

    f32x4 acc[4][4] = {};

    for (int k0 = 0; k0 < D_DIM; k0 += BK) {
        #pragma unroll
        for (int i = 0; i < 4; ++i) {
            GLOAD_LDS16(agp[i] + k0, alp[i]);
            GLOAD_LDS16(bgp[i] + k0, blp[i]);
        }
        __syncthreads();   // compiler drains vmcnt before s_barrier
        #pragma unroll
        for (int kk = 0; kk < 2; ++kk) {
            bf16x8 a[4], b[4];
            #pragma unroll
            for (int m = 0; m < 4; ++m) {
                int R = wr * 64 + m * 16 + lr;
                int cb = (kk * 64 + lk * 16) ^ ((R & 7) << 4);
                a[m] = *(const bf16x8*)((const char*)As + R * 128 + cb);
            }
            #pragma unroll
            for (int n = 0; n < 4; ++n) {
                int R = wc * 64 + n * 16 + lr;
                int cb = (kk * 64 + lk * 16) ^ ((R & 7) << 4);
                b[n] = *(const bf16x8*)((const char*)Bs + R * 128 + cb);
            }
            #pragma unroll
            for (int m = 0; m < 4; ++m)
                #pragma unroll
                for (int n = 0; n < 4; ++n)
                    acc[m][n] = __builtin_amdgcn_mfma_f32_16x16x32_bf16(a[m], b[n], acc[m][n], 0, 0, 0);
        }
        __syncthreads();
    }

    // epilogue: out[t, gn] += w * (acc + bias)
    float bias[4];
    #pragma unroll
    for (int n = 0; n < 4; ++n) {
        int gn = n_base + wc * 64 + n * 16 + lr;
        bias[n] = expert_b[e * D_DIM + gn];
    }
    #pragma unroll
    for (int m = 0; m < 4; ++m) {
        #pragma unroll
        for (int j = 0; j < 4; ++j) {
            int mi = wr * 64 + m * 16 + lk * 4 + j;
            if (m_base + mi >= cnt) continue;
            int tk = tok_s[mi];
            float wgt = w_s[mi];
            size_t obase = (size_t)tk * D_DIM;
            #pragma unroll
            for (int n = 0; n < 4; ++n) {
                int gn = n_base + wc * 64 + n * 16 + lr;
                atomicAdd(out + obase + gn, (acc[m][n][j] + bias[n]) * wgt);
            }
        }
    }
}

extern "C" void kernel_launch(void* const* d_in, const int* in_sizes, int n_in,
                              void* d_out, int out_size, void* d_ws, size_t ws_size,
                              hipStream_t stream) {
    const float* x        = (const float*)d_in[0];
    const float* gate_w   = (const float*)d_in[1];
    const float* gate_b   = (const float*)d_in[2];
    const float* expert_w = (const float*)d_in[3];
    const float* expert_b = (const float*)d_in[4];

    float* out        = (float*)d_out;                      // [T, D]
    float* out_logits = out + (size_t)T_TOK * D_DIM;        // [T, E]
    float* out_sel    = out_logits + (size_t)T_TOK * E_EXP; // [T, 2] as float

    char* ws = (char*)d_ws;
    unsigned short* wbf = (unsigned short*)ws;                         // 16 MB
    unsigned short* xbf = (unsigned short*)(ws + 16777216);            // 32 MB
    int*   counts      = (int*)(ws + 50331648);                        // 2 KB (+pad)
    int*   pair_token  = (int*)(ws + 50331648 + 4096);                 // 512 KB
    float* pair_weight = (float*)(ws + 50331648 + 4096 + 524288);      // 512 KB

    hipMemsetAsync(counts, 0, E_EXP * CNT_STRIDE * sizeof(int), stream);
    hipMemsetAsync(out, 0, (size_t)T_TOK * D_DIM * sizeof(float), stream);

    convert_w_kernel<<<2048, 256, 0, stream>>>(expert_w, wbf);
    router_kernel<<<T_TOK / TPB_TOK, 256, 0, stream>>>(x, gate_w, gate_b, out_logits,
                                                       out_sel, counts, pair_token,
                                                       pair_weight, xbf);
    dim3 grid(D_DIM / BN, T_TOK / BM, E_EXP);
    moe_gemm_kernel<<<grid, 256, 0, stream>>>(xbf, wbf, expert_b, counts,
                                              pair_token, pair_weight, out);
}

// Round 4
// 218.089 us; speedup vs baseline: 3.1263x; 1.0515x over previous
//
#include <hip/hip_runtime.h>
#include <hip/hip_bf16.h>

#define T_TOK 16384
#define D_DIM 1024
#define E_EXP 8

#define BM 128
#define BN 128
#define BK 64            // 128 B/row in bf16
#define NT_K (D_DIM / BK)

#define CNT_STRIDE 64    // pad expert counters to 256B apart

typedef __attribute__((ext_vector_type(4))) float f32x4;
typedef __attribute__((ext_vector_type(8))) short bf16x8;
typedef __attribute__((ext_vector_type(4))) unsigned short u16x4;

static __device__ __forceinline__ unsigned short f2bf(float f) {
    unsigned int u = __float_as_uint(f);
    unsigned int r = 0x7FFFu + ((u >> 16) & 1u);
    return (unsigned short)((u + r) >> 16);
}

// direct-to-LDS 16B async copy: global src per-lane, LDS dest = uniform base + lane*16
#define GLOAD_LDS16(gp, lp) \
    __builtin_amdgcn_global_load_lds( \
        (const __attribute__((address_space(1))) void*)(gp), \
        (__attribute__((address_space(3))) void*)(lp), 16, 0, 0)

// ---------------- expert_w fp32 -> bf16 ----------------
__global__ __launch_bounds__(256) void convert_w_kernel(
    const float* __restrict__ w, unsigned short* __restrict__ o) {
    const int n4 = (E_EXP * D_DIM * D_DIM) / 4;
    for (int i = blockIdx.x * 256 + threadIdx.x; i < n4; i += gridDim.x * 256) {
        f32x4 v = ((const f32x4*)w)[i];
        u16x4 p;
        p[0] = f2bf(v[0]); p[1] = f2bf(v[1]); p[2] = f2bf(v[2]); p[3] = f2bf(v[3]);
        ((u16x4*)o)[i] = p;
    }
}

// ---------------- router: 64 tokens/block + fused x->bf16 ----------------
#define TPB_TOK 64
__global__ __launch_bounds__(256) void router_kernel(
    const float* __restrict__ x, const float* __restrict__ gate_w,
    const float* __restrict__ gate_b, float* __restrict__ out_logits,
    float* __restrict__ out_sel, int* __restrict__ counts,
    int* __restrict__ pair_token, float* __restrict__ pair_weight,
    unsigned short* __restrict__ xbf) {
    __shared__ float gw[E_EXP][D_DIM];          // 32 KB
    __shared__ float gb_s[E_EXP];
    __shared__ float logits_s[TPB_TOK][E_EXP];  // 2 KB
    __shared__ int   cnt_local[E_EXP];
    __shared__ int   gbase[E_EXP];
    __shared__ int   ent_e[TPB_TOK][2];
    __shared__ int   ent_pos[TPB_TOK][2];
    __shared__ float ent_w[TPB_TOK][2];

    const int tid = threadIdx.x;
    for (int i = tid; i < E_EXP * D_DIM; i += 256) gw[0][i] = gate_w[i];
    if (tid < E_EXP) { gb_s[tid] = gate_b[tid]; cnt_local[tid] = 0; }
    __syncthreads();

    const int lane = tid & 63, wv = tid >> 6;
    const int tl = lane >> 2, g = lane & 3;     // 4 lanes per token
    const int jt = wv * 16 + tl;                // token within block [0,64)
    const int t = blockIdx.x * TPB_TOK + jt;

    float acc[E_EXP] = {};
    const f32x4* xr = (const f32x4*)(x + (size_t)t * D_DIM);
    u16x4* xw = (u16x4*)(xbf + (size_t)t * D_DIM);
    for (int i = g; i < D_DIM / 4; i += 4) {
        f32x4 xv = xr[i];
        u16x4 pk;
        pk[0] = f2bf(xv[0]); pk[1] = f2bf(xv[1]); pk[2] = f2bf(xv[2]); pk[3] = f2bf(xv[3]);
        xw[i] = pk;                              // fused fp32->bf16 copy of x
        #pragma unroll
        for (int e = 0; e < E_EXP; ++e) {
            f32x4 gv = ((const f32x4*)(&gw[e][0]))[i];
            acc[e] += xv[0] * gv[0] + xv[1] * gv[1] + xv[2] * gv[2] + xv[3] * gv[3];
        }
    }
    #pragma unroll
    for (int e = 0; e < E_EXP; ++e) {
        float v = acc[e];
        v += __shfl_xor(v, 1, 64);
        v += __shfl_xor(v, 2, 64);
        acc[e] = v;
    }
    if (g == 0) {
        float l[E_EXP], p[E_EXP];
        float m = -1e30f;
        #pragma unroll
        for (int e = 0; e < E_EXP; ++e) { l[e] = acc[e] + gb_s[e]; m = fmaxf(m, l[e]); }
        float s = 0.f;
        #pragma unroll
        for (int e = 0; e < E_EXP; ++e) { p[e] = expf(l[e] - m); s += p[e]; }
        #pragma unroll
        for (int e = 0; e < E_EXP; ++e) p[e] /= s;
        // top-2 on probs, strict > => lowest index wins ties (matches jax.lax.top_k)
        int e0 = 0; float p0 = p[0];
        #pragma unroll
        for (int e = 1; e < E_EXP; ++e) if (p[e] > p0) { p0 = p[e]; e0 = e; }
        int e1 = -1; float p1 = -1e30f;
        #pragma unroll
        for (int e = 0; e < E_EXP; ++e) if (e != e0 && p[e] > p1) { p1 = p[e]; e1 = e; }
        float denom = p0 + p1;
        float w0 = p0 / denom, w1 = p1 / denom;
        #pragma unroll
        for (int e = 0; e < E_EXP; ++e) logits_s[jt][e] = l[e];
        out_sel[t * 2 + 0] = (float)e0;
        out_sel[t * 2 + 1] = (float)e1;
        int p0i = atomicAdd(&cnt_local[e0], 1);   // LDS atomic: cheap
        int p1i = atomicAdd(&cnt_local[e1], 1);
        ent_e[jt][0] = e0; ent_pos[jt][0] = p0i; ent_w[jt][0] = w0;
        ent_e[jt][1] = e1; ent_pos[jt][1] = p1i; ent_w[jt][1] = w1;
    }
    __syncthreads();
    if (tid < E_EXP) gbase[tid] = atomicAdd(&counts[tid * CNT_STRIDE], cnt_local[tid]);
    if (tid < TPB_TOK * E_EXP / 4) {
        f32x4 v = ((const f32x4*)&logits_s[0][0])[tid];
        ((f32x4*)(out_logits + (size_t)blockIdx.x * TPB_TOK * E_EXP))[tid] = v;
    }
    __syncthreads();
    if (g == 0) {
        #pragma unroll
        for (int k = 0; k < 2; ++k) {
            int e = ent_e[jt][k];
            int pos = gbase[e] + ent_pos[jt][k];
            pair_token[e * T_TOK + pos] = t;
            pair_weight[e * T_TOK + pos] = ent_w[jt][k];
        }
    }
}

// ---------------- grouped gather-GEMM, 2-phase double-buffered ----------------
// LDS(row, cb) holds global (row, cb ^ ((row&7)<<4)); both-sides swizzle.
// Flat-grid chunked mapping: the 8 n-tiles of one (m-tile, expert) get flat ids
// congruent mod 8 -> same XCD under round-robin dispatch -> A-tile L2 reuse.
__global__ __launch_bounds__(256, 2) void moe_gemm_kernel(
    const unsigned short* __restrict__ xbf, const unsigned short* __restrict__ wbf,
    const float* __restrict__ expert_b, const int* __restrict__ counts,
    const int* __restrict__ pair_token, const float* __restrict__ pair_weight,
    float* __restrict__ out) {
    const int flat = blockIdx.x;
    const int cls = flat & 7;          // XCD class
    const int nt  = (flat >> 3) & 7;   // n-tile
    const int sup = flat >> 6;
    const int group = sup * 8 + cls;   // (expert, m-tile), bijective
    const int e = group >> 7;
    const int m_base = (group & 127) * BM;
    const int cnt = counts[e * CNT_STRIDE];
    if (m_base >= cnt) return;
    const int n_base = nt * BN;

    __shared__ unsigned short As[2][BM * BK];   // 2 x 16 KB
    __shared__ unsigned short Bs[2][BM * BK];   // 2 x 16 KB
    __shared__ int tok_s[BM];
    __shared__ float w_s[BM];

    const int tid = threadIdx.x;
    if (tid < BM) {
        int m = m_base + tid;
        int mc = (m < cnt) ? m : (cnt - 1);  // clamp: OOB rows compute garbage, skipped in epilogue
        tok_s[tid] = pair_token[e * T_TOK + mc];
        w_s[tid]   = pair_weight[e * T_TOK + mc];
    }
    __syncthreads();

    const int lane = tid & 63;
    const int w = tid >> 6;
    const int lr = lane & 15, lk = lane >> 4;
    const int wr = w >> 1, wc = w & 1;       // 2x2 waves, 64x64 each

    // staging geometry: wave w, issue i covers rows [i*32+w*8, +8), 128 B each
    const int srow = lane >> 3;                       // row within 8-row group
    const int scol = 8 * ((lane & 7) ^ srow);         // swizzled source column (elems)
    const unsigned short* wb = wbf + ((size_t)e << 20);
    const unsigned short* agp[4];
    const unsigned short* bgp[4];
    int loff[4];
    #pragma unroll
    for (int i = 0; i < 4; ++i) {
        int R = i * 32 + w * 8 + srow;
        agp[i] = xbf + (size_t)tok_s[R] * D_DIM + scol;
        bgp[i] = wb + (size_t)(n_base + R) * D_DIM + scol;
        loff[i] = (i * 32 + w * 8) * BK;              // wave-uniform LDS elem offset
    }

    f32x4 acc[4][4] = {};

    // prologue: stage k-tile 0 into buffer 0
    #pragma unroll
    for (int i = 0; i < 4; ++i) {
        GLOAD_LDS16(agp[i], &As[0][loff[i]]);
        GLOAD_LDS16(bgp[i], &Bs[0][loff[i]]);
    }
    __syncthreads();   // drains vmcnt(0): tile 0 resident

#define COMPUTE_TILE(cur) \
    do { \
        const char* Ab = (const char*)&As[(cur)][0]; \
        const char* Bb = (const char*)&Bs[(cur)][0]; \
        _Pragma("unroll") \
        for (int kk = 0; kk < 2; ++kk) { \
            bf16x8 a[4], b[4]; \
            _Pragma("unroll") \
            for (int m = 0; m < 4; ++m) { \
                int R = wr * 64 + m * 16 + lr; \
                int cb = (kk * 64 + lk * 16) ^ ((R & 7) << 4); \
                a[m] = *(const bf16x8*)(Ab + R * 128 + cb); \
            } \
            _Pragma("unroll") \
            for (int n = 0; n < 4; ++n) { \
                int R = wc * 64 + n * 16 + lr; \
                int cb = (kk * 64 + lk * 16) ^ ((R & 7) << 4); \
                b[n] = *(const bf16x8*)(Bb + R * 128 + cb); \
            } \
            _Pragma("unroll") \
            for (int m = 0; m < 4; ++m) \
                _Pragma("unroll") \
                for (int n = 0; n < 4; ++n) \
                    acc[m][n] = __builtin_amdgcn_mfma_f32_16x16x32_bf16(a[m], b[n], acc[m][n], 0, 0, 0); \
        } \
    } while (0)

    #pragma unroll
    for (int t = 0; t < NT_K - 1; ++t) {
        const int cur = t & 1, nxt = cur ^ 1;
        const int k0n = (t + 1) * BK;
        // issue next tile's loads FIRST: latency hides under current tile's MFMA
        #pragma unroll
        for (int i = 0; i < 4; ++i) {
            GLOAD_LDS16(agp[i] + k0n, &As[nxt][loff[i]]);
            GLOAD_LDS16(bgp[i] + k0n, &Bs[nxt][loff[i]]);
        }
        COMPUTE_TILE(cur);
        __syncthreads();   // one drain+barrier per K-step: next tile ready, cur free
    }
    COMPUTE_TILE((NT_K - 1) & 1);
#undef COMPUTE_TILE

    // epilogue: out[t, gn] += w * (acc + bias)
    float bias[4];
    #pragma unroll
    for (int n = 0; n < 4; ++n) {
        int gn = n_base + wc * 64 + n * 16 + lr;
        bias[n] = expert_b[e * D_DIM + gn];
    }
    #pragma unroll
    for (int m = 0; m < 4; ++m) {
        #pragma unroll
        for (int j = 0; j < 4; ++j) {
            int mi = wr * 64 + m * 16 + lk * 4 + j;
            if (m_base + mi >= cnt) continue;
            int tk = tok_s[mi];
            float wgt = w_s[mi];
            size_t obase = (size_t)tk * D_DIM;
            #pragma unroll
            for (int n = 0; n < 4; ++n) {
                int gn = n_base + wc * 64 + n * 16 + lr;
                atomicAdd(out + obase + gn, (acc[m][n][j] + bias[n]) * wgt);
            }
        }
    }
}

extern "C" void kernel_launch(void* const* d_in, const int* in_sizes, int n_in,
                              void* d_out, int out_size, void* d_ws, size_t ws_size,
                              hipStream_t stream) {
    const float* x        = (const float*)d_in[0];
    const float* gate_w   = (const float*)d_in[1];
    const float* gate_b   = (const float*)d_in[2];
    const float* expert_w = (const float*)d_in[3];
    const float* expert_b = (const float*)d_in[4];

    float* out        = (float*)d_out;                      // [T, D]
    float* out_logits = out + (size_t)T_TOK * D_DIM;        // [T, E]
    float* out_sel    = out_logits + (size_t)T_TOK * E_EXP; // [T, 2] as float

    char* ws = (char*)d_ws;
    unsigned short* wbf = (unsigned short*)ws;                         // 16 MB
    unsigned short* xbf = (unsigned short*)(ws + 16777216);            // 32 MB
    int*   counts      = (int*)(ws + 50331648);                        // 2 KB (+pad)
    int*   pair_token  = (int*)(ws + 50331648 + 4096);                 // 512 KB
    float* pair_weight = (float*)(ws + 50331648 + 4096 + 524288);      // 512 KB

    hipMemsetAsync(counts, 0, E_EXP * CNT_STRIDE * sizeof(int), stream);
    hipMemsetAsync(out, 0, (size_t)T_TOK * D_DIM * sizeof(float), stream);

    convert_w_kernel<<<2048, 256, 0, stream>>>(expert_w, wbf);
    router_kernel<<<T_TOK / TPB_TOK, 256, 0, stream>>>(x, gate_w, gate_b, out_logits,
                                                       out_sel, counts, pair_token,
                                                       pair_weight, xbf);
    moe_gemm_kernel<<<(D_DIM / BN) * (T_TOK / BM) * E_EXP, 256, 0, stream>>>(
        xbf, wbf, expert_b, counts, pair_token, pair_weight, out);
}

// Round 5
// 213.064 us; speedup vs baseline: 3.2000x; 1.0236x over previous
//
#include <hip/hip_runtime.h>
#include <hip/hip_bf16.h>

#define T_TOK 16384
#define D_DIM 1024
#define E_EXP 8

#define BM 128
#define BN 128
#define BK 64            // 128 B/row in bf16
#define NT_K (D_DIM / BK)

#define CNT_STRIDE 64    // pad expert counters to 256B apart

typedef __attribute__((ext_vector_type(4))) float f32x4;
typedef __attribute__((ext_vector_type(8))) short bf16x8;
typedef __attribute__((ext_vector_type(4))) unsigned short u16x4;

static __device__ __forceinline__ unsigned short f2bf(float f) {
    unsigned int u = __float_as_uint(f);
    unsigned int r = 0x7FFFu + ((u >> 16) & 1u);
    return (unsigned short)((u + r) >> 16);
}

// direct-to-LDS 16B async copy: global src per-lane, LDS dest = uniform base + lane*16
#define GLOAD_LDS16(gp, lp) \
    __builtin_amdgcn_global_load_lds( \
        (const __attribute__((address_space(1))) void*)(gp), \
        (__attribute__((address_space(3))) void*)(lp), 16, 0, 0)

// ---------------- expert_w fp32 -> bf16 ----------------
__global__ __launch_bounds__(256) void convert_w_kernel(
    const float* __restrict__ w, unsigned short* __restrict__ o) {
    const int n4 = (E_EXP * D_DIM * D_DIM) / 4;
    for (int i = blockIdx.x * 256 + threadIdx.x; i < n4; i += gridDim.x * 256) {
        f32x4 v = ((const f32x4*)w)[i];
        u16x4 p;
        p[0] = f2bf(v[0]); p[1] = f2bf(v[1]); p[2] = f2bf(v[2]); p[3] = f2bf(v[3]);
        ((u16x4*)o)[i] = p;
    }
}

// ---------------- router: 64 tokens/block + fused x->bf16 ----------------
#define TPB_TOK 64
__global__ __launch_bounds__(256) void router_kernel(
    const float* __restrict__ x, const float* __restrict__ gate_w,
    const float* __restrict__ gate_b, float* __restrict__ out_logits,
    float* __restrict__ out_sel, int* __restrict__ counts,
    int* __restrict__ pair_token, float* __restrict__ pair_weight,
    unsigned short* __restrict__ xbf) {
    __shared__ float gw[E_EXP][D_DIM];          // 32 KB
    __shared__ float gb_s[E_EXP];
    __shared__ float logits_s[TPB_TOK][E_EXP];  // 2 KB
    __shared__ int   cnt_local[E_EXP];
    __shared__ int   gbase[E_EXP];
    __shared__ int   ent_e[TPB_TOK][2];
    __shared__ int   ent_pos[TPB_TOK][2];
    __shared__ float ent_w[TPB_TOK][2];

    const int tid = threadIdx.x;
    for (int i = tid; i < E_EXP * D_DIM; i += 256) gw[0][i] = gate_w[i];
    if (tid < E_EXP) { gb_s[tid] = gate_b[tid]; cnt_local[tid] = 0; }
    __syncthreads();

    const int lane = tid & 63, wv = tid >> 6;
    const int tl = lane >> 2, g = lane & 3;     // 4 lanes per token
    const int jt = wv * 16 + tl;                // token within block [0,64)
    const int t = blockIdx.x * TPB_TOK + jt;

    float acc[E_EXP] = {};
    const f32x4* xr = (const f32x4*)(x + (size_t)t * D_DIM);
    u16x4* xw = (u16x4*)(xbf + (size_t)t * D_DIM);
    for (int i = g; i < D_DIM / 4; i += 4) {
        f32x4 xv = xr[i];
        u16x4 pk;
        pk[0] = f2bf(xv[0]); pk[1] = f2bf(xv[1]); pk[2] = f2bf(xv[2]); pk[3] = f2bf(xv[3]);
        xw[i] = pk;                              // fused fp32->bf16 copy of x
        #pragma unroll
        for (int e = 0; e < E_EXP; ++e) {
            f32x4 gv = ((const f32x4*)(&gw[e][0]))[i];
            acc[e] += xv[0] * gv[0] + xv[1] * gv[1] + xv[2] * gv[2] + xv[3] * gv[3];
        }
    }
    #pragma unroll
    for (int e = 0; e < E_EXP; ++e) {
        float v = acc[e];
        v += __shfl_xor(v, 1, 64);
        v += __shfl_xor(v, 2, 64);
        acc[e] = v;
    }
    if (g == 0) {
        float l[E_EXP], p[E_EXP];
        float m = -1e30f;
        #pragma unroll
        for (int e = 0; e < E_EXP; ++e) { l[e] = acc[e] + gb_s[e]; m = fmaxf(m, l[e]); }
        float s = 0.f;
        #pragma unroll
        for (int e = 0; e < E_EXP; ++e) { p[e] = expf(l[e] - m); s += p[e]; }
        #pragma unroll
        for (int e = 0; e < E_EXP; ++e) p[e] /= s;
        // top-2 on probs, strict > => lowest index wins ties (matches jax.lax.top_k)
        int e0 = 0; float p0 = p[0];
        #pragma unroll
        for (int e = 1; e < E_EXP; ++e) if (p[e] > p0) { p0 = p[e]; e0 = e; }
        int e1 = -1; float p1 = -1e30f;
        #pragma unroll
        for (int e = 0; e < E_EXP; ++e) if (e != e0 && p[e] > p1) { p1 = p[e]; e1 = e; }
        float denom = p0 + p1;
        float w0 = p0 / denom, w1 = p1 / denom;
        #pragma unroll
        for (int e = 0; e < E_EXP; ++e) logits_s[jt][e] = l[e];
        out_sel[t * 2 + 0] = (float)e0;
        out_sel[t * 2 + 1] = (float)e1;
        int p0i = atomicAdd(&cnt_local[e0], 1);   // LDS atomic: cheap
        int p1i = atomicAdd(&cnt_local[e1], 1);
        ent_e[jt][0] = e0; ent_pos[jt][0] = p0i; ent_w[jt][0] = w0;
        ent_e[jt][1] = e1; ent_pos[jt][1] = p1i; ent_w[jt][1] = w1;
    }
    __syncthreads();
    if (tid < E_EXP) gbase[tid] = atomicAdd(&counts[tid * CNT_STRIDE], cnt_local[tid]);
    if (tid < TPB_TOK * E_EXP / 4) {
        f32x4 v = ((const f32x4*)&logits_s[0][0])[tid];
        ((f32x4*)(out_logits + (size_t)blockIdx.x * TPB_TOK * E_EXP))[tid] = v;
    }
    __syncthreads();
    if (g == 0) {
        #pragma unroll
        for (int k = 0; k < 2; ++k) {
            int e = ent_e[jt][k];
            int pos = gbase[e] + ent_pos[jt][k];
            pair_token[e * T_TOK + pos] = t;
            pair_weight[e * T_TOK + pos] = ent_w[jt][k];
        }
    }
}

// ---------------- grouped gather-GEMM, 2-phase dbuf + COUNTED vmcnt ----------------
// LDS(row, cb) holds global (row, cb ^ ((row&7)<<4)); both-sides swizzle.
// T4: s_waitcnt vmcnt(8) leaves next tile's 8 loads in flight across the barrier;
// raw s_barrier (no implicit vmcnt drain). lgkmcnt(0) before barrier B makes the
// buffer overwrite safe (each wave's ds_reads complete before signaling).
__global__ __launch_bounds__(256, 2) void moe_gemm_kernel(
    const unsigned short* __restrict__ xbf, const unsigned short* __restrict__ wbf,
    const float* __restrict__ expert_b, const int* __restrict__ counts,
    const int* __restrict__ pair_token, const float* __restrict__ pair_weight,
    float* __restrict__ out) {
    const int flat = blockIdx.x;
    const int cls = flat & 7;          // XCD class
    const int nt  = (flat >> 3) & 7;   // n-tile
    const int sup = flat >> 6;
    const int group = sup * 8 + cls;   // (expert, m-tile), bijective
    const int e = group >> 7;
    const int m_base = (group & 127) * BM;
    const int cnt = counts[e * CNT_STRIDE];
    if (m_base >= cnt) return;
    const int n_base = nt * BN;

    __shared__ unsigned short As[2][BM * BK];   // 2 x 16 KB
    __shared__ unsigned short Bs[2][BM * BK];   // 2 x 16 KB
    __shared__ int tok_s[BM];
    __shared__ float w_s[BM];

    const int tid = threadIdx.x;
    if (tid < BM) {
        int m = m_base + tid;
        int mc = (m < cnt) ? m : (cnt - 1);  // clamp: OOB rows compute garbage, skipped in epilogue
        tok_s[tid] = pair_token[e * T_TOK + mc];
        w_s[tid]   = pair_weight[e * T_TOK + mc];
    }
    __syncthreads();

    const int lane = tid & 63;
    const int w = tid >> 6;
    const int lr = lane & 15, lk = lane >> 4;
    const int wr = w >> 1, wc = w & 1;       // 2x2 waves, 64x64 each

    // staging geometry: wave w, issue i covers rows [i*32+w*8, +8), 128 B each
    const int srow = lane >> 3;                       // row within 8-row group
    const int scol = 8 * ((lane & 7) ^ srow);         // swizzled source column (elems)
    const unsigned short* wb = wbf + ((size_t)e << 20);
    const unsigned short* agp[4];
    const unsigned short* bgp[4];
    int loff[4];
    #pragma unroll
    for (int i = 0; i < 4; ++i) {
        int R = i * 32 + w * 8 + srow;
        agp[i] = xbf + (size_t)tok_s[R] * D_DIM + scol;
        bgp[i] = wb + (size_t)(n_base + R) * D_DIM + scol;
        loff[i] = (i * 32 + w * 8) * BK;              // wave-uniform LDS elem offset
    }

    f32x4 acc[4][4] = {};

#define STAGE(buf, k0s) \
    do { \
        _Pragma("unroll") \
        for (int i = 0; i < 4; ++i) { \
            GLOAD_LDS16(agp[i] + (k0s), &As[(buf)][loff[i]]); \
            GLOAD_LDS16(bgp[i] + (k0s), &Bs[(buf)][loff[i]]); \
        } \
    } while (0)

#define COMPUTE_TILE(cur) \
    do { \
        const char* Ab = (const char*)&As[(cur)][0]; \
        const char* Bb = (const char*)&Bs[(cur)][0]; \
        _Pragma("unroll") \
        for (int kk = 0; kk < 2; ++kk) { \
            bf16x8 a[4], b[4]; \
            _Pragma("unroll") \
            for (int m = 0; m < 4; ++m) { \
                int R = wr * 64 + m * 16 + lr; \
                int cb = (kk * 64 + lk * 16) ^ ((R & 7) << 4); \
                a[m] = *(const bf16x8*)(Ab + R * 128 + cb); \
            } \
            _Pragma("unroll") \
            for (int n = 0; n < 4; ++n) { \
                int R = wc * 64 + n * 16 + lr; \
                int cb = (kk * 64 + lk * 16) ^ ((R & 7) << 4); \
                b[n] = *(const bf16x8*)(Bb + R * 128 + cb); \
            } \
            _Pragma("unroll") \
            for (int m = 0; m < 4; ++m) \
                _Pragma("unroll") \
                for (int n = 0; n < 4; ++n) \
                    acc[m][n] = __builtin_amdgcn_mfma_f32_16x16x32_bf16(a[m], b[n], acc[m][n], 0, 0, 0); \
        } \
    } while (0)

    // prologue: stage k-tile 0 into buffer 0
    STAGE(0, 0);

    #pragma unroll
    for (int t = 0; t < NT_K; ++t) {
        const int cur = t & 1;
        if (t < NT_K - 1) {
            STAGE(cur ^ 1, (t + 1) * BK);                 // 8 loads in flight
            asm volatile("s_waitcnt vmcnt(8)" ::: "memory");   // cur tile resident (mine)
        } else {
            asm volatile("s_waitcnt vmcnt(0)" ::: "memory");
        }
        __builtin_amdgcn_s_barrier();                     // cur tile resident (all waves)
        COMPUTE_TILE(cur);
        asm volatile("s_waitcnt lgkmcnt(0)" ::: "memory"); // my ds_reads of cur done
        __builtin_amdgcn_s_barrier();                     // cur buffer free to overwrite
    }
#undef COMPUTE_TILE
#undef STAGE

    // epilogue: out[t, gn] += w * (acc + bias)
    float bias[4];
    #pragma unroll
    for (int n = 0; n < 4; ++n) {
        int gn = n_base + wc * 64 + n * 16 + lr;
        bias[n] = expert_b[e * D_DIM + gn];
    }
    #pragma unroll
    for (int m = 0; m < 4; ++m) {
        #pragma unroll
        for (int j = 0; j < 4; ++j) {
            int mi = wr * 64 + m * 16 + lk * 4 + j;
            if (m_base + mi >= cnt) continue;
            int tk = tok_s[mi];
            float wgt = w_s[mi];
            size_t obase = (size_t)tk * D_DIM;
            #pragma unroll
            for (int n = 0; n < 4; ++n) {
                int gn = n_base + wc * 64 + n * 16 + lr;
                atomicAdd(out + obase + gn, (acc[m][n][j] + bias[n]) * wgt);
            }
        }
    }
}

extern "C" void kernel_launch(void* const* d_in, const int* in_sizes, int n_in,
                              void* d_out, int out_size, void* d_ws, size_t ws_size,
                              hipStream_t stream) {
    const float* x        = (const float*)d_in[0];
    const float* gate_w   = (const float*)d_in[1];
    const float* gate_b   = (const float*)d_in[2];
    const float* expert_w = (const float*)d_in[3];
    const float* expert_b = (const float*)d_in[4];

    float* out        = (float*)d_out;                      // [T, D]
    float* out_logits = out + (size_t)T_TOK * D_DIM;        // [T, E]
    float* out_sel    = out_logits + (size_t)T_TOK * E_EXP; // [T, 2] as float

    char* ws = (char*)d_ws;
    unsigned short* wbf = (unsigned short*)ws;                         // 16 MB
    unsigned short* xbf = (unsigned short*)(ws + 16777216);            // 32 MB
    int*   counts      = (int*)(ws + 50331648);                        // 2 KB (+pad)
    int*   pair_token  = (int*)(ws + 50331648 + 4096);                 // 512 KB
    float* pair_weight = (float*)(ws + 50331648 + 4096 + 524288);      // 512 KB

    hipMemsetAsync(counts, 0, E_EXP * CNT_STRIDE * sizeof(int), stream);
    hipMemsetAsync(out, 0, (size_t)T_TOK * D_DIM * sizeof(float), stream);

    convert_w_kernel<<<2048, 256, 0, stream>>>(expert_w, wbf);
    router_kernel<<<T_TOK / TPB_TOK, 256, 0, stream>>>(x, gate_w, gate_b, out_logits,
                                                       out_sel, counts, pair_token,
                                                       pair_weight, xbf);
    moe_gemm_kernel<<<(D_DIM / BN) * (T_TOK / BM) * E_EXP, 256, 0, stream>>>(
        xbf, wbf, expert_b, counts, pair_token, pair_weight, out);
}